// Round 3
// baseline (351.364 us; speedup 1.0000x reference)
//
#include <hip/hip_runtime.h>

#define NB 64      // batch
#define SEQ 305    // sequence length
#define DIM 2048   // hidden
#define NP 256     // patches
#define NT 48      // task tokens
#define NKEEP 128  // kept patches
#define SOUT 177   // 1 + 128 + 48
#define KS 16      // K-step per LDS chunk

static_assert(1 + NP + NT == SEQ, "layout");

constexpr float kScale = 0.022097086912079608f;  // 1/sqrt(2048)

// ---------------------------------------------------------------------------
// K1a: split-K partial GEMM, tile M=256(all patches) x N=48, micro-tile 8x6.
// grid (ndc, 64). 256 threads: pg = t>>3 (32 x 8 rows), tg = t&7 (8 x 6 cols).
// LDS reads per dd: 2x b128 (p) + b128+b64 (t, 8-slot padded) = 42 cyc for
// 48 FMAs. Writes partial R transposed [48][256] (coalesced both sides) and
// per-staging-slot partial ssq (deterministic fixed-order reduce in k1b).
// ---------------------------------------------------------------------------
__global__ __launch_bounds__(256, 4) void k1a_partial_gemm(
    const float* __restrict__ tokens, float* __restrict__ rpart,
    float* __restrict__ ssqP, float* __restrict__ ssqT, int ndc, int dchunk) {
  const int dci = blockIdx.x;
  const int b = blockIdx.y;
  const int t = threadIdx.x;

  __shared__ float pC[KS][260];  // [d][patch-row], stride 260 (16B-mult, 2-way max)
  __shared__ float tC[KS][64];   // [d][t-slot]: group g at g*8 + 0..5

  const float* pbase = tokens + ((size_t)b * SEQ + 1) * DIM + (size_t)dci * dchunk;
  const float* tbase = tokens + ((size_t)b * SEQ + 1 + NP) * DIM + (size_t)dci * dchunk;

  const int pg = t >> 3;  // 0..31
  const int tg = t & 7;   // 0..7

  float acc[8][6] = {};
  float ssqa[5] = {0.f, 0.f, 0.f, 0.f, 0.f};
  float4 st[5];

  const int nchunk = dchunk >> 4;

  // preload chunk 0: slots u = t + 256l; u<1024: p(prow=u>>2, c4=u&3), else t
#pragma unroll
  for (int l = 0; l < 5; ++l) {
    int u = t + 256 * l;
    if (u < 1024) {
      int prow = u >> 2, c4 = u & 3;
      st[l] = *(const float4*)(pbase + (size_t)prow * DIM + c4 * 4);
    } else if (u < 1216) {
      int v = u - 1024;
      int trow = v >> 2, c4 = v & 3;
      st[l] = *(const float4*)(tbase + (size_t)trow * DIM + c4 * 4);
    }
  }

  for (int ck = 0; ck < nchunk; ++ck) {
    __syncthreads();  // previous compute done reading LDS
#pragma unroll
    for (int l = 0; l < 5; ++l) {
      int u = t + 256 * l;
      float4 v = st[l];
      if (u < 1024) {
        int prow = u >> 2, c4 = u & 3;
        pC[c4 * 4 + 0][prow] = v.x;
        pC[c4 * 4 + 1][prow] = v.y;
        pC[c4 * 4 + 2][prow] = v.z;
        pC[c4 * 4 + 3][prow] = v.w;
        ssqa[l] += v.x * v.x + v.y * v.y + v.z * v.z + v.w * v.w;
      } else if (u < 1216) {
        int vv = u - 1024;
        int trow = vv >> 2, c4 = vv & 3;
        int slot = (trow / 6) * 8 + (trow % 6);
        tC[c4 * 4 + 0][slot] = v.x;
        tC[c4 * 4 + 1][slot] = v.y;
        tC[c4 * 4 + 2][slot] = v.z;
        tC[c4 * 4 + 3][slot] = v.w;
        ssqa[l] += v.x * v.x + v.y * v.y + v.z * v.z + v.w * v.w;
      }
    }
    __syncthreads();
    // issue next chunk's global loads (latency hidden under compute below)
    if (ck + 1 < nchunk) {
      const float* pb2 = pbase + (ck + 1) * KS;
      const float* tb2 = tbase + (ck + 1) * KS;
#pragma unroll
      for (int l = 0; l < 5; ++l) {
        int u = t + 256 * l;
        if (u < 1024) {
          int prow = u >> 2, c4 = u & 3;
          st[l] = *(const float4*)(pb2 + (size_t)prow * DIM + c4 * 4);
        } else if (u < 1216) {
          int v = u - 1024;
          int trow = v >> 2, c4 = v & 3;
          st[l] = *(const float4*)(tb2 + (size_t)trow * DIM + c4 * 4);
        }
      }
    }
#pragma unroll
    for (int dd = 0; dd < KS; ++dd) {
      float4 p0 = *(const float4*)&pC[dd][pg * 8];
      float4 p1 = *(const float4*)&pC[dd][pg * 8 + 4];
      float4 t0 = *(const float4*)&tC[dd][tg * 8];
      float2 t1 = *(const float2*)&tC[dd][tg * 8 + 4];
      float pa[8] = {p0.x, p0.y, p0.z, p0.w, p1.x, p1.y, p1.z, p1.w};
      float tb[6] = {t0.x, t0.y, t0.z, t0.w, t1.x, t1.y};
#pragma unroll
      for (int i = 0; i < 8; ++i)
#pragma unroll
        for (int j = 0; j < 6; ++j) acc[i][j] += pa[i] * tb[j];
    }
  }

  // store partial R transposed: rpart[(b*ndc+dci)][jg][256]
  float* rp = rpart + ((size_t)b * ndc + dci) * (48 * 256);
#pragma unroll
  for (int j = 0; j < 6; ++j) {
    int jg = tg * 6 + j;
    float4 v0 = {acc[0][j], acc[1][j], acc[2][j], acc[3][j]};
    float4 v1 = {acc[4][j], acc[5][j], acc[6][j], acc[7][j]};
    *(float4*)(rp + jg * 256 + pg * 8) = v0;
    *(float4*)(rp + jg * 256 + pg * 8 + 4) = v1;
  }
  // store per-slot partial ssq
  float* sp = ssqP + ((size_t)b * ndc + dci) * 1024;
  float* stt = ssqT + ((size_t)b * ndc + dci) * 192;
#pragma unroll
  for (int l = 0; l < 5; ++l) {
    int u = t + 256 * l;
    if (u < 1024) sp[u] = ssqa[l];
    else if (u < 1216) stt[u - 1024] = ssqa[l];
  }
}

// ---------------------------------------------------------------------------
// K1b: grid (4 pt, 64 b), 256 thr. Sum ndc partials in fixed order
// (deterministic), rms + softmax, write attnp = softmax*invT and
// rn = raw*invP (both [b][p][48]). Inits umax.
// Thread (r = t&63, q = t>>6) accumulates cols q*12..q*12+11 of row pt*64+r.
// ---------------------------------------------------------------------------
__global__ __launch_bounds__(256) void k1b_reduce_softmax(
    const float* __restrict__ rpart, const float* __restrict__ ssqP,
    const float* __restrict__ ssqT, float* __restrict__ attnp,
    float* __restrict__ rn, unsigned long long* __restrict__ umax, int ndc) {
  const int pt = blockIdx.x;
  const int b = blockIdx.y;
  const int t = threadIdx.x;
  const int r = t & 63;
  const int q = t >> 6;

  __shared__ float L[64][49];
  __shared__ float invPs[64];
  __shared__ float invTs[48];

  float a[12] = {};
  const float* rb = rpart + (size_t)b * ndc * (48 * 256) + pt * 64 + r;
  for (int dci = 0; dci < ndc; ++dci) {
    const float* rp = rb + (size_t)dci * (48 * 256);
#pragma unroll
    for (int j = 0; j < 12; ++j) a[j] += rp[(q * 12 + j) * 256];
  }
#pragma unroll
  for (int j = 0; j < 12; ++j) L[r][q * 12 + j] = a[j];

  if (t < 64) {
    float s = 0.f;
    for (int dci = 0; dci < ndc; ++dci) {
      const float* sp = ssqP + ((size_t)b * ndc + dci) * 1024 + (pt * 64 + t) * 4;
      s += sp[0] + sp[1] + sp[2] + sp[3];
    }
    invPs[t] = 1.0f / sqrtf(s * (1.0f / 2048.0f) + 1e-6f);
    umax[(size_t)b * NP + pt * 64 + t] = 0ull;
  } else if (t < 112) {
    int j = t - 64;
    float s = 0.f;
    for (int dci = 0; dci < ndc; ++dci) {
      const float* stt = ssqT + ((size_t)b * ndc + dci) * 192 + j * 4;
      s += stt[0] + stt[1] + stt[2] + stt[3];
    }
    invTs[j] = 1.0f / sqrtf(s * (1.0f / 2048.0f) + 1e-6f);
  }
  __syncthreads();

  if (t < 64) {
    const float invp = invPs[t];
    float lg[48];
    float m = -3.4e38f;
#pragma unroll
    for (int j = 0; j < 48; ++j) {
      lg[j] = L[t][j] * invp * invTs[j] * kScale;
      m = fmaxf(m, lg[j]);
    }
    float s = 0.f;
#pragma unroll
    for (int j = 0; j < 48; ++j) {
      lg[j] = expf(lg[j] - m);
      s += lg[j];
    }
    const float is = 1.0f / s;
    float* ao = attnp + ((size_t)b * NP + pt * 64 + t) * NT;
    float* ro = rn + ((size_t)b * NP + pt * 64 + t) * NT;
#pragma unroll
    for (int j = 0; j < 48; ++j) ao[j] = lg[j] * is * invTs[j];
#pragma unroll
    for (int j = 0; j < 48; ++j) ro[j] = L[t][j] * invp;
  }
}

// ---------------------------------------------------------------------------
// K2: score[p][q] = sum_t attn'[p][t] * Rn[q][t], argmax over q folded in via
// packed (mono-float | ~q) atomicMax (order-independent -> deterministic).
// ---------------------------------------------------------------------------
__global__ __launch_bounds__(256) void k2_score_argmax(
    const float* __restrict__ attnp, const float* __restrict__ rn,
    unsigned long long* __restrict__ umax) {
  const int b = blockIdx.y;
  const int qt = blockIdx.x & 3;
  const int pb = blockIdx.x >> 2;
  const int t = threadIdx.x;
  const int tp = t >> 4, tq = t & 15;

  __shared__ float aS[48][68];
  __shared__ float rS[48][68];

  const float* ab = attnp + ((size_t)b * NP + pb * 64) * NT;
  const float* rb = rn + ((size_t)b * NP + qt * 64) * NT;
#pragma unroll
  for (int l = 0; l < 3; ++l) {
    int u = t + 256 * l;  // 64 rows x 12 f4
    int row = u / 12, c4 = u % 12;
    float4 v = *(const float4*)(ab + (size_t)row * NT + c4 * 4);
    aS[c4 * 4 + 0][row] = v.x;
    aS[c4 * 4 + 1][row] = v.y;
    aS[c4 * 4 + 2][row] = v.z;
    aS[c4 * 4 + 3][row] = v.w;
    float4 w = *(const float4*)(rb + (size_t)row * NT + c4 * 4);
    rS[c4 * 4 + 0][row] = w.x;
    rS[c4 * 4 + 1][row] = w.y;
    rS[c4 * 4 + 2][row] = w.z;
    rS[c4 * 4 + 3][row] = w.w;
  }
  __syncthreads();

  float acc[4][4] = {};
#pragma unroll
  for (int k = 0; k < 48; ++k) {
    float4 av = *(const float4*)&aS[k][tp * 4];
    float4 rv = *(const float4*)&rS[k][tq * 4];
    float aa[4] = {av.x, av.y, av.z, av.w};
    float rr[4] = {rv.x, rv.y, rv.z, rv.w};
#pragma unroll
    for (int i = 0; i < 4; ++i)
#pragma unroll
      for (int j = 0; j < 4; ++j) acc[i][j] += aa[i] * rr[j];
  }

#pragma unroll
  for (int i = 0; i < 4; ++i) {
    float bs = acc[i][0];
    int bq = qt * 64 + tq * 4;
#pragma unroll
    for (int j = 1; j < 4; ++j) {
      float s = acc[i][j];
      int qq = qt * 64 + tq * 4 + j;
      if (s > bs) {  // strict > keeps smallest q on ties
        bs = s;
        bq = qq;
      }
    }
    unsigned us = __float_as_uint(bs);
    us = (us & 0x80000000u) ? ~us : (us | 0x80000000u);
    unsigned long long key =
        ((unsigned long long)us << 32) | (unsigned long long)(0xFFFFFFFFu - (unsigned)bq);
    for (int o = 8; o >= 1; o >>= 1) {
      unsigned long long ok = __shfl_xor(key, o, 16);
      if (ok > key) key = ok;
    }
    if (tq == 0) atomicMax(&umax[(size_t)b * NP + pb * 64 + tp * 4 + i], key);
  }
}

// ---------------------------------------------------------------------------
// K3: per batch: decode argmax, vote counts, exact rank (count desc, idx asc),
// keep rank<128, emit ascending; then gather pos/mask in the same block.
// ---------------------------------------------------------------------------
__global__ __launch_bounds__(256) void k3_select_meta(
    const unsigned long long* __restrict__ umax, const int* __restrict__ pos,
    const int* __restrict__ msk, int* __restrict__ order,
    float* __restrict__ out1, float* __restrict__ out2) {
  const int b = blockIdx.x, t = threadIdx.x;
  __shared__ int cnt[256];
  __shared__ int kept[256];
  __shared__ int sorder[NKEEP];
  cnt[t] = 0;
  __syncthreads();
  unsigned long long key = umax[(size_t)b * NP + t];
  int q = (int)(0xFFFFFFFFu - (unsigned)(key & 0xFFFFFFFFull));
  atomicAdd(&cnt[q], 1);
  __syncthreads();
  const int c = cnt[t];
  int rank = 0;
  for (int u = 0; u < 256; ++u) {
    int cu = cnt[u];
    rank += (cu > c || (cu == c && u < t)) ? 1 : 0;
  }
  kept[t] = (rank < NKEEP) ? 1 : 0;
  __syncthreads();
  if (kept[t]) {
    int posn = 0;
    for (int u = 0; u < t; ++u) posn += kept[u];
    order[b * NKEEP + posn] = t;
    sorder[posn] = t;
  }
  __syncthreads();
  if (t < SOUT) {
    int src;
    if (t == 0) src = 0;
    else if (t < 1 + NKEEP) src = 1 + sorder[t - 1];
    else src = t + (NP - NKEEP);
    out1[b * SOUT + t] = (float)pos[b * SEQ + src];
    out2[b * SOUT + t] = (float)msk[b * SEQ + src];
  }
}

// ---------------------------------------------------------------------------
// K4: gather token rows (exact copies) into packed output.
// ---------------------------------------------------------------------------
__global__ __launch_bounds__(256) void k4_gather_tokens(
    const float* __restrict__ tokens, const int* __restrict__ order,
    float* __restrict__ out) {
  const int s = blockIdx.x;  // 0..176
  const int b = blockIdx.y;
  const int t = threadIdx.x;
  int src;
  if (s == 0) src = 0;
  else if (s < 1 + NKEEP) src = 1 + order[b * NKEEP + (s - 1)];
  else src = s + (NP - NKEEP);
  const float4* in4 = (const float4*)(tokens + ((size_t)b * SEQ + src) * DIM);
  float4* o4 = (float4*)(out + ((size_t)b * SOUT + s) * DIM);
  o4[t] = in4[t];
  o4[t + 256] = in4[t + 256];
}

// ---------------------------------------------------------------------------
extern "C" void kernel_launch(void* const* d_in, const int* in_sizes, int n_in,
                              void* d_out, int out_size, void* d_ws,
                              size_t ws_size, hipStream_t stream) {
  const float* tokens = (const float*)d_in[0];
  const int* pos = (const int*)d_in[1];
  const int* msk = (const int*)d_in[2];

  float* out0 = (float*)d_out;
  float* out1 = out0 + (size_t)NB * SOUT * DIM;
  float* out2 = out1 + (size_t)NB * SOUT;

  // adaptive split-K depth by workspace size
  const size_t fixed = (size_t)(2 * NB * NP * NT) * 4 + (size_t)NB * NP * 8 +
                       (size_t)NB * NKEEP * 4;
  const size_t perndc = (size_t)NB * (48 * 256 + 1024 + 192) * 4;
  int ndc = 16;
  while (ndc > 4 && fixed + (size_t)ndc * perndc > ws_size) ndc >>= 1;
  const int dchunk = DIM / ndc;

  char* ws = (char*)d_ws;
  float* attnp = (float*)ws;                 // NB*NP*NT
  float* rn = attnp + (size_t)NB * NP * NT;  // NB*NP*NT
  unsigned long long* umax = (unsigned long long*)(rn + (size_t)NB * NP * NT);
  int* order = (int*)(umax + (size_t)NB * NP);
  float* rpart = (float*)(order + (size_t)NB * NKEEP);       // NB*ndc*48*256
  float* ssqP = rpart + (size_t)NB * ndc * 48 * 256;         // NB*ndc*1024
  float* ssqT = ssqP + (size_t)NB * ndc * 1024;              // NB*ndc*192

  k1a_partial_gemm<<<dim3(ndc, NB), 256, 0, stream>>>(tokens, rpart, ssqP,
                                                      ssqT, ndc, dchunk);
  k1b_reduce_softmax<<<dim3(4, NB), 256, 0, stream>>>(rpart, ssqP, ssqT, attnp,
                                                      rn, umax, ndc);
  k2_score_argmax<<<dim3(16, NB), 256, 0, stream>>>(attnp, rn, umax);
  k3_select_meta<<<NB, 256, 0, stream>>>(umax, pos, msk, order, out1, out2);
  k4_gather_tokens<<<dim3(SOUT, NB), 256, 0, stream>>>(tokens, order, out0);
}